// Round 4
// baseline (988.967 us; speedup 1.0000x reference)
//
#include <hip/hip_runtime.h>

typedef unsigned short u16;
typedef __bf16 bf16x8 __attribute__((ext_vector_type(8)));
typedef float f32x4 __attribute__((ext_vector_type(4)));

static __device__ __forceinline__ f32x4 mfma16(bf16x8 a, bf16x8 b, f32x4 c) {
  return __builtin_amdgcn_mfma_f32_16x16x32_bf16(a, b, c, 0, 0, 0);
}

static __device__ __forceinline__ u16 f2bf(float f) {
  union { float f; unsigned u; } v; v.f = f;
  unsigned r = v.u + 0x7fffu + ((v.u >> 16) & 1u);
  return (u16)(r >> 16);
}

static __device__ __forceinline__ unsigned pk2(float a, float b) {
  return (unsigned)f2bf(a) | ((unsigned)f2bf(b) << 16);
}

// async global->LDS DMA, 16B per lane; dest must be wave-uniform base (linear fill)
static __device__ __forceinline__ void gl2lds16(const u16* g, u16* l) {
  __builtin_amdgcn_global_load_lds(
      (const __attribute__((address_space(1))) unsigned int*)g,
      (__attribute__((address_space(3))) unsigned int*)l, 16, 0, 0);
}

// ---------------- mask element-size probe ----------------
__global__ void k_flag(const unsigned char* __restrict__ m, int* flag) {
  int t = threadIdx.x;  // 64 threads
  unsigned v = (unsigned)m[4*t+1] | (unsigned)m[4*t+2] | (unsigned)m[4*t+3];
  unsigned long long any = __ballot(v != 0);
  if (t == 0) *flag = (any == 0ull) ? 1 : 0;
}

// ---------------- mask bit-pack: elem -> 1 bit ----------------
__global__ __launch_bounds__(256) void k_pack(const void* __restrict__ m,
                                              const int* __restrict__ flagp,
                                              unsigned* __restrict__ out) {
  int flag = *flagp;
  int lane = threadIdx.x & 63, wv = threadIdx.x >> 6;
  long base = (long)blockIdx.x * 2048 + wv * 64 + lane;
#pragma unroll
  for (int it = 0; it < 8; ++it) {
    long elem = base + it * 256;
    bool pred = flag ? (((const int*)m)[elem] != 0)
                     : (((const unsigned char*)m)[elem] != 0);
    unsigned long long bal = __ballot(pred);
    if (lane == 0)  out[elem >> 5] = (unsigned)bal;
    if (lane == 32) out[elem >> 5] = (unsigned)(bal >> 32);
  }
}

// ---------------- weight transpose+convert: W[d][e] -> Wt[e][d] bf16 ----------------
__global__ __launch_bounds__(256) void k_wtr(const float* __restrict__ Wq,
                                             const float* __restrict__ Wk,
                                             const float* __restrict__ Wv,
                                             u16* __restrict__ Wt) {
  int m = blockIdx.z;
  const float* src = (m < 12) ? (Wq + (size_t)m * 65536)
                   : (m < 24) ? (Wk + (size_t)(m - 12) * 65536)
                              : (Wv + (size_t)(m - 24) * 65536);
  u16* dst = Wt + (size_t)m * 65536;
  __shared__ float T[64][65];
  int t = threadIdx.x;
  int d0 = blockIdx.x * 64, e0 = blockIdx.y * 64;
  for (int it = 0; it < 16; ++it) {
    int idx = it * 256 + t; int r = idx >> 6, c = idx & 63;
    T[r][c] = src[(size_t)(d0 + r) * 256 + e0 + c];
  }
  __syncthreads();
  for (int it = 0; it < 16; ++it) {
    int idx = it * 256 + t; int r = idx >> 6, c = idx & 63;
    dst[(size_t)(e0 + r) * 256 + d0 + c] = f2bf(T[c][r]);
  }
}

// ---------------- fp32 -> bf16 convert (+ optional fp32 copy) ----------------
__global__ __launch_bounds__(256) void k_cvt(const float* __restrict__ src,
                                             u16* __restrict__ db,
                                             float* dstf, long n) {
  long i = ((long)blockIdx.x * 256 + threadIdx.x) * 4;
  if (i >= n) return;
  float4 v = *(const float4*)(src + i);
  union { u16 u[4]; uint2 q; } o;
  o.u[0] = f2bf(v.x); o.u[1] = f2bf(v.y); o.u[2] = f2bf(v.z); o.u[3] = f2bf(v.w);
  *(uint2*)(db + i) = o.q;
  if (dstf) *(float4*)(dstf + i) = v;
}

// ---------------- fused 3-linear chain body: Ws double-buffer, 1 barrier/kk ----------------
template<int MODE>
static __device__ __forceinline__ void gemm3_body(
    const u16* __restrict__ X, const u16* __restrict__ Wt,
    const float* __restrict__ bias, u16* __restrict__ out, int Nk,
    long row0, u16 (*Xs)[264], u16 (*Ws)[256][40]) {
  int t = threadIdx.x, lane = t & 63, w = t >> 6, g = lane >> 4, li = lane & 15;
  int n4 = t >> 2, cp = t & 3;

  for (int it = 0; it < 8; ++it) {
    int c = it * 256 + t, r = c >> 5, k8 = (c & 31) << 3;
    *(uint4*)&Xs[r][k8] = *(const uint4*)&X[(row0 + r) * 256 + k8];
  }

  for (int j = 0; j < 3; ++j) {
    const u16* Wj = Wt + j * 65536;
    uint4 wr[4];
#pragma unroll
    for (int it = 0; it < 4; ++it)
      wr[it] = *(const uint4*)&Wj[(it * 64 + n4) * 256 + cp * 8];
#pragma unroll
    for (int it = 0; it < 4; ++it)
      *(uint4*)&Ws[0][it * 64 + n4][cp << 3] = wr[it];
    __syncthreads();

    f32x4 acc[4][4];
#pragma unroll
    for (int i = 0; i < 4; ++i)
#pragma unroll
      for (int jj = 0; jj < 4; ++jj) acc[i][jj] = (f32x4){0.f, 0.f, 0.f, 0.f};

    for (int kk = 0; kk < 8; ++kk) {
      int p = kk & 1;
      if (kk < 7) {
#pragma unroll
        for (int it = 0; it < 4; ++it)
          wr[it] = *(const uint4*)&Wj[(it * 64 + n4) * 256 + (kk + 1) * 32 + cp * 8];
      }
      bf16x8 xf[4], wf[4];
#pragma unroll
      for (int f = 0; f < 4; ++f) xf[f] = *(const bf16x8*)&Xs[f * 16 + li][kk * 32 + g * 8];
#pragma unroll
      for (int f = 0; f < 4; ++f) wf[f] = *(const bf16x8*)&Ws[p][w * 64 + f * 16 + li][g * 8];
#pragma unroll
      for (int i = 0; i < 4; ++i)
#pragma unroll
        for (int jj = 0; jj < 4; ++jj)
          acc[i][jj] = (MODE == 0) ? mfma16(xf[i], wf[jj], acc[i][jj])
                                   : mfma16(wf[i], xf[jj], acc[i][jj]);
      if (kk < 7) {
#pragma unroll
        for (int it = 0; it < 4; ++it)
          *(uint4*)&Ws[p ^ 1][it * 64 + n4][cp << 3] = wr[it];
      }
      __syncthreads();
    }
    if (j < 2) {
#pragma unroll
      for (int i = 0; i < 4; ++i)
#pragma unroll
        for (int jj = 0; jj < 4; ++jj)
#pragma unroll
          for (int r = 0; r < 4; ++r) {
            int R, C;
            if (MODE == 0) { R = i * 16 + g * 4 + r; C = w * 64 + jj * 16 + li; }
            else           { R = jj * 16 + li;       C = w * 64 + i * 16 + g * 4 + r; }
            Xs[R][C] = f2bf(acc[i][jj][r] + bias[j * 256 + C]);
          }
      __syncthreads();
    } else {
      if (MODE == 0) {
#pragma unroll
        for (int i = 0; i < 4; ++i)
#pragma unroll
          for (int jj = 0; jj < 4; ++jj)
#pragma unroll
            for (int r = 0; r < 4; ++r) {
              int R = i * 16 + g * 4 + r, C = w * 64 + jj * 16 + li;
              out[(row0 + R) * 256 + C] = f2bf(acc[i][jj][r] + bias[512 + C]);
            }
      } else {
        long b = row0 / Nk, rb = row0 - b * Nk;
#pragma unroll
        for (int i = 0; i < 4; ++i)
#pragma unroll
          for (int jj = 0; jj < 4; ++jj)
#pragma unroll
            for (int r = 0; r < 4; ++r) {
              int e = w * 64 + i * 16 + g * 4 + r, xr = jj * 16 + li;
              out[(b * 256 + e) * (long)Nk + rb + xr] = f2bf(acc[i][jj][r] + bias[512 + e]);
            }
      }
    }
  }
}

// One dispatch per layer: Q-proj + K-proj + V-proj blocks co-resident.
__global__ __launch_bounds__(256, 2) void k_gemm3f(
    const u16* __restrict__ Xq, const u16* __restrict__ Xkv,
    const u16* __restrict__ Wt, const float* __restrict__ bq,
    const float* __restrict__ bk, const float* __restrict__ bv,
    u16* __restrict__ Qb, u16* __restrict__ Kb, u16* __restrict__ Vt,
    int layer, int Mkv, int Nk) {
  __shared__ __align__(16) u16 Xs[64][264];
  __shared__ __align__(16) u16 Ws[2][256][40];
  int u = blockIdx.x;
  if (u < 256)
    gemm3_body<0>(Xq, Wt + (size_t)layer * 3 * 65536, bq + layer * 768, Qb, 0,
                  (long)u * 64, Xs, Ws);
  else if (u < 256 + Mkv)
    gemm3_body<0>(Xkv, Wt + (size_t)(12 + layer * 3) * 65536, bk + layer * 768, Kb, 0,
                  (long)(u - 256) * 64, Xs, Ws);
  else
    gemm3_body<1>(Xkv, Wt + (size_t)(24 + layer * 3) * 65536, bv + layer * 768, Vt, Nk,
                  (long)(u - 256 - Mkv) * 64, Xs, Ws);
}

// ---------------- flash attention v5: 32q/wave, DMA dbuf, 1 barrier/iter ----------------
// Grid 256 x 512thr (64 q-rows/block). 8 waves: w -> (qt = w>>2, s = w&3).
// Wave: 32 q-rows (2 q-frag sets), k-quarter s (16k of each 64k chunk).
// K/V staged by global_load_lds (pre-swizzled global source, linear LDS dest,
// swizzled read), double-buffered. QK swapped (S[k][q] lane-local); P redistributed
// in-register; PV uses zero-padded P frag (k 16..31 = 0) to keep K=32 MFMA.
// Epilogue: 2-round LDS tree merge of the 4 k-quarter partials, LN, +residual.
#define OIDX(ql, d) (((ql) << 8) + ((((d) + ((ql) << 2))) & 255))
__global__ __launch_bounds__(512, 2) void k_attn(
    const u16* __restrict__ Qb, const u16* __restrict__ Kb, const u16* __restrict__ Vt,
    const unsigned* __restrict__ Mb,
    const float* __restrict__ gamma, const float* __restrict__ beta,
    float* xres, u16* xbout,
    const float* __restrict__ future, float* __restrict__ dout, int last, int Nk) {
  __shared__ __align__(16) char RAW[132096];   // K dbuf 64KB | V dbuf 64KB | Lp 1KB
  u16* Ksh = (u16*)RAW;                        // [2][64][256]
  u16* Vsh = (u16*)(RAW + 65536);              // [2][256][64]
  float* Lp = (float*)(RAW + 131072);          // [3][64]

  int t = threadIdx.x, lane = t & 63, w = t >> 6;
  int qt = w >> 2, s = w & 3;
  int g = lane >> 4, li = lane & 15;
  int sw = li & 7;

  // XCD-bijective swizzle: XCD x owns batches {2x,2x+1} -> K/V stays in its L2.
  int n = blockIdx.x;
  int b = ((n & 7) << 1) | ((n >> 3) & 1);
  int q0 = (n >> 4) << 6;

  int Wm = Nk >> 5, nc = Nk >> 6;

  const u16* Kg = Kb + (long)b * Nk * 256;
  const u16* Vg = Vt + (long)b * 256 * (long)Nk;
  int row0q = b * 1024 + q0 + qt * 32;
  const unsigned* Mr0 = Mb + (long)(row0q + li) * Wm;
  const unsigned* Mr1 = Mb + (long)(row0q + 16 + li) * Wm;
  const u16* Qg0 = Qb + (long)(row0q + li) * 256 + g * 8;
  const u16* Qg1 = Qb + (long)(row0q + 16 + li) * 256 + g * 8;

  // DMA per-lane pre-swizzled source offsets (K: [64][256], V: [256][64] tiles)
  int kr0 = (w << 1) | (lane >> 5);                       // 0..15
  long kOff = (long)kr0 * 256 + (((lane & 31) ^ (kr0 & 7)) << 3);
  int vd0 = (w << 3) | (lane >> 3);                       // 0..63
  long vOff = (long)vd0 * Nk + (((lane & 7) ^ (vd0 & 7)) << 3);
  int dOff = w << 9;                                      // wave's LDS slot base (u16)

  // ---- prologue: DMA chunk 0 -> buf0; Q frags from global ----
#pragma unroll
  for (int c = 0; c < 4; ++c) {
    gl2lds16(Kg + kOff + (long)c * 4096, Ksh + c * 4096 + dOff);
    gl2lds16(Vg + vOff + (long)c * 64 * Nk, Vsh + c * 4096 + dOff);
  }
  bf16x8 qf0[8], qf1[8];
#pragma unroll
  for (int kc = 0; kc < 8; ++kc) {
    qf0[kc] = *(const bf16x8*)(Qg0 + kc * 32);
    qf1[kc] = *(const bf16x8*)(Qg1 + kc * 32);
  }
  f32x4 O0[16], O1[16];
#pragma unroll
  for (int dt = 0; dt < 16; ++dt) {
    O0[dt] = (f32x4){0.f, 0.f, 0.f, 0.f};
    O1[dt] = (f32x4){0.f, 0.f, 0.f, 0.f};
  }
  float ls0 = 0.f, ls1 = 0.f;
  asm volatile("s_waitcnt vmcnt(0)" ::: "memory");
  __syncthreads();

  for (int ci = 0; ci < nc; ++ci) {
    int p = ci & 1;
    if (ci + 1 < nc) {   // issue next chunk's DMA into the other buffer
      const u16* Kc = Kg + (long)(ci + 1) * 64 * 256;
      const u16* Vc = Vg + (long)(ci + 1) * 64;
      u16* KB = Ksh + (p ^ 1) * 16384;
      u16* VB = Vsh + (p ^ 1) * 16384;
#pragma unroll
      for (int c = 0; c < 4; ++c) {
        gl2lds16(Kc + kOff + (long)c * 4096, KB + c * 4096 + dOff);
        gl2lds16(Vc + vOff + (long)c * 64 * Nk, VB + c * 4096 + dOff);
      }
    }
    unsigned mw0 = Mr0[(ci << 1) + (s >> 1)];
    unsigned mw1 = Mr1[(ci << 1) + (s >> 1)];
    const u16* Kp = Ksh + p * 16384 + (s * 16 + li) * 256;
    const u16* Vp = Vsh + p * 16384;

    // QK^T swapped: st[u]: S[k = s*16 + g*4 + r][q = qt*32 + u*16 + li]
    f32x4 st0 = (f32x4){0.f, 0.f, 0.f, 0.f}, st1 = (f32x4){0.f, 0.f, 0.f, 0.f};
#pragma unroll
    for (int kc = 0; kc < 8; ++kc) {
      bf16x8 kf = *(const bf16x8*)&Kp[((kc * 4 + g) ^ sw) << 3];
      st0 = mfma16(kf, qf0[kc], st0);
      st1 = mfma16(kf, qf1[kc], st1);
    }
    float e0[4], e1[4];
#pragma unroll
    for (int r = 0; r < 4; ++r) {
      int bit = ((s & 1) << 4) + g * 4 + r;
      e0[r] = ((mw0 >> bit) & 1u) ? 0.f : __expf(st0[r] * 0.0625f);
      e1[r] = ((mw1 >> bit) & 1u) ? 0.f : __expf(st1[r] * 0.0625f);
      ls0 += e0[r]; ls1 += e1[r];
    }
    unsigned p00 = pk2(e0[0], e0[1]), p01 = pk2(e0[2], e0[3]);
    unsigned p10 = pk2(e1[0], e1[1]), p11 = pk2(e1[2], e1[3]);
    // redistribute: lane (g<2,li): P[q][frag-k = g*8..g*8+7]; frag-k 16..31 zero-padded
    int base = ((g & 1) << 5) + li;
    unsigned a0 = __shfl(p00, base),      a1 = __shfl(p01, base);
    unsigned a2 = __shfl(p00, base + 16), a3 = __shfl(p01, base + 16);
    unsigned b0 = __shfl(p10, base),      b1 = __shfl(p11, base);
    unsigned b2 = __shfl(p10, base + 16), b3 = __shfl(p11, base + 16);
    bool lo = (g < 2);
    union { unsigned u[4]; bf16x8 v; } pa0, pa1;
    pa0.u[0] = lo ? a0 : 0u; pa0.u[1] = lo ? a1 : 0u;
    pa0.u[2] = lo ? a2 : 0u; pa0.u[3] = lo ? a3 : 0u;
    pa1.u[0] = lo ? b0 : 0u; pa1.u[1] = lo ? b1 : 0u;
    pa1.u[2] = lo ? b2 : 0u; pa1.u[3] = lo ? b3 : 0u;
    // PV: O[q][d = dt*16+li] over this wave's 16k slice (V rows from swizzled LDS)
    int vco = ((s * 2 + (g & 1)) ^ sw) << 3;
#pragma unroll
    for (int dt = 0; dt < 16; ++dt) {
      bf16x8 bv = *(const bf16x8*)&Vp[(dt * 16 + li) * 64 + vco];
      O0[dt] = mfma16(pa0.v, bv, O0[dt]);
      O1[dt] = mfma16(pa1.v, bv, O1[dt]);
    }
    asm volatile("s_waitcnt vmcnt(0)" ::: "memory");
    __syncthreads();
  }

  // ---- epilogue: merge 4 k-quarter partials (2-round LDS tree), LN, +residual ----
  ls0 += __shfl_xor(ls0, 16); ls0 += __shfl_xor(ls0, 32);
  ls1 += __shfl_xor(ls1, 16); ls1 += __shfl_xor(ls1, 32);
  if (s >= 1 && lane < 16) {
    Lp[(s - 1) * 64 + qt * 32 + lane] = ls0;
    Lp[(s - 1) * 64 + qt * 32 + 16 + lane] = ls1;
  }
  float* Slot = (float*)RAW;   // 4 slots x 32KB (aliases K/V dbuf)
  if (s >= 2) {
    float* P = Slot + (((s - 2) << 1) + qt) * 8192;
#pragma unroll
    for (int dt = 0; dt < 16; ++dt)
#pragma unroll
      for (int r = 0; r < 4; ++r) {
        P[OIDX(g * 4 + r, dt * 16 + li)] = O0[dt][r];
        P[OIDX(16 + g * 4 + r, dt * 16 + li)] = O1[dt][r];
      }
  }
  __syncthreads();
  if (s < 2) {
    float* P = Slot + ((s << 1) + qt) * 8192;
#pragma unroll
    for (int dt = 0; dt < 16; ++dt)
#pragma unroll
      for (int r = 0; r < 4; ++r) {
        O0[dt][r] += P[OIDX(g * 4 + r, dt * 16 + li)];
        O1[dt][r] += P[OIDX(16 + g * 4 + r, dt * 16 + li)];
      }
  }
  __syncthreads();
  if (s == 1) {
    float* P = Slot + qt * 8192;
#pragma unroll
    for (int dt = 0; dt < 16; ++dt)
#pragma unroll
      for (int r = 0; r < 4; ++r) {
        P[OIDX(g * 4 + r, dt * 16 + li)] = O0[dt][r];
        P[OIDX(16 + g * 4 + r, dt * 16 + li)] = O1[dt][r];
      }
  }
  __syncthreads();
  if (s == 0) {
    float* P = Slot + qt * 8192;
#pragma unroll
    for (int dt = 0; dt < 16; ++dt)
#pragma unroll
      for (int r = 0; r < 4; ++r) {
        O0[dt][r] += P[OIDX(g * 4 + r, dt * 16 + li)];
        O1[dt][r] += P[OIDX(16 + g * 4 + r, dt * 16 + li)];
      }
    float lt0 = ls0 + Lp[qt * 32 + li] + Lp[64 + qt * 32 + li] + Lp[128 + qt * 32 + li];
    float lt1 = ls1 + Lp[qt * 32 + 16 + li] + Lp[64 + qt * 32 + 16 + li]
              + Lp[128 + qt * 32 + 16 + li];
    float rl0 = 1.f / fmaxf(lt0, 1e-30f);
    float rl1 = 1.f / fmaxf(lt1, 1e-30f);
    float rq0[4], rq1[4];
#pragma unroll
    for (int r = 0; r < 4; ++r) {
      rq0[r] = __shfl(rl0, g * 4 + r);
      rq1[r] = __shfl(rl1, g * 4 + r);
    }
    float sm0[4] = {0.f,0.f,0.f,0.f}, s20[4] = {0.f,0.f,0.f,0.f};
    float sm1[4] = {0.f,0.f,0.f,0.f}, s21[4] = {0.f,0.f,0.f,0.f};
#pragma unroll
    for (int dt = 0; dt < 16; ++dt)
#pragma unroll
      for (int r = 0; r < 4; ++r) {
        float y0 = O0[dt][r] * rq0[r]; O0[dt][r] = y0; sm0[r] += y0; s20[r] += y0 * y0;
        float y1 = O1[dt][r] * rq1[r]; O1[dt][r] = y1; sm1[r] += y1; s21[r] += y1 * y1;
      }
    float mu0[4], rs0[4], mu1[4], rs1[4];
#pragma unroll
    for (int r = 0; r < 4; ++r) {
      float a0 = sm0[r], c0 = s20[r], a1 = sm1[r], c1 = s21[r];
      a0 += __shfl_xor(a0, 1); a0 += __shfl_xor(a0, 2); a0 += __shfl_xor(a0, 4); a0 += __shfl_xor(a0, 8);
      c0 += __shfl_xor(c0, 1); c0 += __shfl_xor(c0, 2); c0 += __shfl_xor(c0, 4); c0 += __shfl_xor(c0, 8);
      a1 += __shfl_xor(a1, 1); a1 += __shfl_xor(a1, 2); a1 += __shfl_xor(a1, 4); a1 += __shfl_xor(a1, 8);
      c1 += __shfl_xor(c1, 1); c1 += __shfl_xor(c1, 2); c1 += __shfl_xor(c1, 4); c1 += __shfl_xor(c1, 8);
      float m0 = a0 * (1.f / 256.f), m1 = a1 * (1.f / 256.f);
      mu0[r] = m0; rs0[r] = rsqrtf(c0 * (1.f / 256.f) - m0 * m0 + 1e-5f);
      mu1[r] = m1; rs1[r] = rsqrtf(c1 * (1.f / 256.f) - m1 * m1 + 1e-5f);
    }
#pragma unroll
    for (int dt = 0; dt < 16; ++dt) {
      int d = dt * 16 + li;
      float gm = gamma[d], bt = beta[d];
#pragma unroll
      for (int r = 0; r < 4; ++r) {
        int q = q0 + qt * 32 + g * 4 + r;
        long idx = ((long)b * 1024 + q) * 256 + d;
        float o = (O0[dt][r] - mu0[r]) * rs0[r] * gm + bt + xres[idx];
        if (last) dout[idx] = o + future[idx];
        else { xres[idx] = o; xbout[idx] = f2bf(o); }
        int q1 = q + 16;
        long idx1 = ((long)b * 1024 + q1) * 256 + d;
        float o1 = (O1[dt][r] - mu1[r]) * rs1[r] * gm + bt + xres[idx1];
        if (last) dout[idx1] = o1 + future[idx1];
        else { xres[idx1] = o1; xbout[idx1] = f2bf(o1); }
      }
    }
  }
}

// ---------------- host ----------------
extern "C" void kernel_launch(void* const* d_in, const int* in_sizes, int n_in,
                              void* d_out, int out_size, void* d_ws, size_t ws_size,
                              hipStream_t stream) {
  const float* future  = (const float*)d_in[0];
  const float* history = (const float*)d_in[1];
  const float* graph   = (const float*)d_in[2];
  const void*  mask_hf = d_in[3];
  const void*  mask_fg = d_in[4];
  const float* Wq = (const float*)d_in[5];
  const float* bq = (const float*)d_in[6];
  const float* Wk = (const float*)d_in[7];
  const float* bk = (const float*)d_in[8];
  const float* Wv = (const float*)d_in[9];
  const float* bv = (const float*)d_in[10];
  const float* gamma = (const float*)d_in[11];
  const float* beta  = (const float*)d_in[12];
  float* dout = (float*)d_out;

  char* ws = (char*)d_ws;
  size_t off = 0;
  int* flag = (int*)(ws + off); off += 256;
  u16* Wt = (u16*)(ws + off);  off += (size_t)36 * 65536 * 2;
  u16* xb = (u16*)(ws + off);  off += (size_t)16384 * 256 * 2;
  float* x = (float*)(ws + off); off += (size_t)16384 * 256 * 4;
  u16* hb = (u16*)(ws + off);  off += (size_t)16384 * 256 * 2;
  u16* gb = (u16*)(ws + off);  off += (size_t)32768 * 256 * 2;
  u16* Qb = (u16*)(ws + off);  off += (size_t)16384 * 256 * 2;
  u16* Kb = (u16*)(ws + off);  off += (size_t)32768 * 256 * 2;
  u16* Vtb = (u16*)(ws + off); off += (size_t)32768 * 256 * 2;
  unsigned* Mbhf = (unsigned*)(ws + off); off += (size_t)16 * 1024 * 1024 / 8;
  unsigned* Mbfg = (unsigned*)(ws + off); off += (size_t)16 * 1024 * 2048 / 8;
  if (ws_size < off) return;

  k_flag<<<1, 64, 0, stream>>>((const unsigned char*)mask_hf, flag);
  k_pack<<<8192, 256, 0, stream>>>(mask_hf, flag, Mbhf);
  k_pack<<<16384, 256, 0, stream>>>(mask_fg, flag, Mbfg);
  k_wtr<<<dim3(4, 4, 36), 256, 0, stream>>>(Wq, Wk, Wv, Wt);
  k_cvt<<<4096, 256, 0, stream>>>(future, xb, x, 4194304L);
  k_cvt<<<4096, 256, 0, stream>>>(history, hb, nullptr, 4194304L);
  k_cvt<<<8192, 256, 0, stream>>>(graph, gb, nullptr, 8388608L);

  for (int i = 0; i < 4; ++i) {
    const u16* src = (i < 2) ? hb : gb;
    int Mkv = (i < 2) ? 256 : 512;
    int Nk = (i < 2) ? 1024 : 2048;
    const unsigned* mb = (i < 2) ? Mbhf : Mbfg;
    k_gemm3f<<<256 + 2 * Mkv, 256, 0, stream>>>(xb, src, Wt, bq, bk, bv,
                                                Qb, Kb, Vtb, i, Mkv, Nk);
    k_attn<<<256, 512, 0, stream>>>(Qb, Kb, Vtb, mb, gamma + i * 256, beta + i * 256,
                                    x, xb, future, dout, (i == 3) ? 1 : 0, Nk);
  }
}

// Round 5
// 773.285 us; speedup vs baseline: 1.2789x; 1.2789x over previous
//
#include <hip/hip_runtime.h>

typedef unsigned short u16;
typedef __bf16 bf16x8 __attribute__((ext_vector_type(8)));
typedef float f32x4 __attribute__((ext_vector_type(4)));

static __device__ __forceinline__ f32x4 mfma16(bf16x8 a, bf16x8 b, f32x4 c) {
  return __builtin_amdgcn_mfma_f32_16x16x32_bf16(a, b, c, 0, 0, 0);
}

static __device__ __forceinline__ u16 f2bf(float f) {
  union { float f; unsigned u; } v; v.f = f;
  unsigned r = v.u + 0x7fffu + ((v.u >> 16) & 1u);
  return (u16)(r >> 16);
}

// ---------------- mask element-size probe ----------------
__global__ void k_flag(const unsigned char* __restrict__ m, int* flag) {
  int t = threadIdx.x;  // 64 threads
  unsigned v = (unsigned)m[4*t+1] | (unsigned)m[4*t+2] | (unsigned)m[4*t+3];
  unsigned long long any = __ballot(v != 0);
  if (t == 0) *flag = (any == 0ull) ? 1 : 0;
}

// ---------------- mask bit-pack: elem -> 1 bit ----------------
__global__ __launch_bounds__(256) void k_pack(const void* __restrict__ m,
                                              const int* __restrict__ flagp,
                                              unsigned* __restrict__ out) {
  int flag = *flagp;
  int lane = threadIdx.x & 63, wv = threadIdx.x >> 6;
  long base = (long)blockIdx.x * 2048 + wv * 64 + lane;
#pragma unroll
  for (int it = 0; it < 8; ++it) {
    long elem = base + it * 256;
    bool pred = flag ? (((const int*)m)[elem] != 0)
                     : (((const unsigned char*)m)[elem] != 0);
    unsigned long long bal = __ballot(pred);
    if (lane == 0)  out[elem >> 5] = (unsigned)bal;
    if (lane == 32) out[elem >> 5] = (unsigned)(bal >> 32);
  }
}

// ---------------- weight composition: Weff = W0*W1*W2 (fp32), beff likewise ----------
static __device__ __forceinline__ const float* wbase(int p, const float* Wq,
                                                     const float* Wk, const float* Wv) {
  return (p < 4) ? (Wq + (size_t)p * 196608)
       : (p < 8) ? (Wk + (size_t)(p - 4) * 196608)
                 : (Wv + (size_t)(p - 8) * 196608);
}

// T[p][r][c] = sum_d W0[r][d] * W1[d][c]   (fp32)
__global__ __launch_bounds__(256) void k_wc1(const float* __restrict__ Wq,
                                             const float* __restrict__ Wk,
                                             const float* __restrict__ Wv,
                                             float* __restrict__ T) {
  int p = blockIdx.y, r = blockIdx.x, c = threadIdx.x;
  const float* W0 = wbase(p, Wq, Wk, Wv);
  const float* W1 = W0 + 65536;
  const float* w0r = W0 + (size_t)r * 256;
  float a0 = 0.f, a1 = 0.f, a2 = 0.f, a3 = 0.f;
  for (int d = 0; d < 256; d += 4) {
    a0 += w0r[d]     * W1[(size_t)d * 256 + c];
    a1 += w0r[d + 1] * W1[(size_t)(d + 1) * 256 + c];
    a2 += w0r[d + 2] * W1[(size_t)(d + 2) * 256 + c];
    a3 += w0r[d + 3] * W1[(size_t)(d + 3) * 256 + c];
  }
  T[((size_t)p * 256 + r) * 256 + c] = (a0 + a1) + (a2 + a3);
}

// Wt[p][e][d] = bf16( sum_c T[p][d][c] * W2[c][e] )   (transposed-out for the GEMM)
__global__ __launch_bounds__(256) void k_wc2(const float* __restrict__ Wq,
                                             const float* __restrict__ Wk,
                                             const float* __restrict__ Wv,
                                             const float* __restrict__ T,
                                             u16* __restrict__ Wt) {
  int p = blockIdx.y, e0 = blockIdx.x << 4, d = threadIdx.x;
  const float* W2 = wbase(p, Wq, Wk, Wv) + 131072;
  __shared__ __align__(16) float sw[256][16];
#pragma unroll
  for (int j = 0; j < 4; ++j)
    *(float4*)&sw[d][j * 4] = *(const float4*)&W2[(size_t)d * 256 + e0 + j * 4];
  __syncthreads();
  const float* Tr = T + ((size_t)p * 256 + d) * 256;
  float acc[16];
#pragma unroll
  for (int j = 0; j < 16; ++j) acc[j] = 0.f;
  for (int c = 0; c < 256; c += 4) {
    float4 tv = *(const float4*)&Tr[c];
#pragma unroll
    for (int j = 0; j < 16; ++j) {
      acc[j] += tv.x * sw[c][j];
      acc[j] += tv.y * sw[c + 1][j];
      acc[j] += tv.z * sw[c + 2][j];
      acc[j] += tv.w * sw[c + 3][j];
    }
  }
#pragma unroll
  for (int j = 0; j < 16; ++j)
    Wt[((size_t)p * 256 + e0 + j) * 256 + d] = f2bf(acc[j]);
}

// beff[p][e] = ((b0*W1 + b1)*W2 + b2)[e]
__global__ __launch_bounds__(256) void k_bc(const float* __restrict__ Wq,
                                            const float* __restrict__ Wk,
                                            const float* __restrict__ Wv,
                                            const float* __restrict__ bq,
                                            const float* __restrict__ bk,
                                            const float* __restrict__ bv,
                                            float* __restrict__ beff) {
  int p = blockIdx.x, t = threadIdx.x;
  const float* W0 = wbase(p, Wq, Wk, Wv);
  const float* W1 = W0 + 65536;
  const float* W2 = W0 + 131072;
  const float* b = (p < 4) ? (bq + p * 768)
                 : (p < 8) ? (bk + (p - 4) * 768)
                           : (bv + (p - 8) * 768);
  __shared__ float s1[256];
  float a = 0.f;
  for (int d = 0; d < 256; ++d) a += b[d] * W1[(size_t)d * 256 + t];
  s1[t] = a + b[256 + t];
  __syncthreads();
  float a2 = 0.f;
  for (int c = 0; c < 256; ++c) a2 += s1[c] * W2[(size_t)c * 256 + t];
  beff[p * 256 + t] = a2 + b[512 + t];
}

// ---------------- fp32 -> bf16 convert (+ optional fp32 copy) ----------------
__global__ __launch_bounds__(256) void k_cvt(const float* __restrict__ src,
                                             u16* __restrict__ db,
                                             float* dstf, long n) {
  long i = ((long)blockIdx.x * 256 + threadIdx.x) * 4;
  if (i >= n) return;
  float4 v = *(const float4*)(src + i);
  union { u16 u[4]; uint2 q; } o;
  o.u[0] = f2bf(v.x); o.u[1] = f2bf(v.y); o.u[2] = f2bf(v.z); o.u[3] = f2bf(v.w);
  *(uint2*)(db + i) = o.q;
  if (dstf) *(float4*)(dstf + i) = v;
}

// ---------------- single-GEMM projection (composed weights), Ws dbuf, 1 barrier/kk ----
template<int MODE>
static __device__ __forceinline__ void gemm1_body(
    const u16* __restrict__ X, const u16* __restrict__ Wj,
    const float* __restrict__ bias, u16* __restrict__ out, int Nk,
    long row0, u16 (*Xs)[264], u16 (*Ws)[256][40]) {
  int t = threadIdx.x, lane = t & 63, w = t >> 6, g = lane >> 4, li = lane & 15;
  int n4 = t >> 2, cp = t & 3;

  for (int it = 0; it < 8; ++it) {
    int c = it * 256 + t, r = c >> 5, k8 = (c & 31) << 3;
    *(uint4*)&Xs[r][k8] = *(const uint4*)&X[(row0 + r) * 256 + k8];
  }

  uint4 wr[4];
#pragma unroll
  for (int it = 0; it < 4; ++it)
    wr[it] = *(const uint4*)&Wj[(it * 64 + n4) * 256 + cp * 8];
#pragma unroll
  for (int it = 0; it < 4; ++it)
    *(uint4*)&Ws[0][it * 64 + n4][cp << 3] = wr[it];
  __syncthreads();

  f32x4 acc[4][4];
#pragma unroll
  for (int i = 0; i < 4; ++i)
#pragma unroll
    for (int jj = 0; jj < 4; ++jj) acc[i][jj] = (f32x4){0.f, 0.f, 0.f, 0.f};

  for (int kk = 0; kk < 8; ++kk) {
    int p = kk & 1;
    if (kk < 7) {
#pragma unroll
      for (int it = 0; it < 4; ++it)
        wr[it] = *(const uint4*)&Wj[(it * 64 + n4) * 256 + (kk + 1) * 32 + cp * 8];
    }
    bf16x8 xf[4], wf[4];
#pragma unroll
    for (int f = 0; f < 4; ++f) xf[f] = *(const bf16x8*)&Xs[f * 16 + li][kk * 32 + g * 8];
#pragma unroll
    for (int f = 0; f < 4; ++f) wf[f] = *(const bf16x8*)&Ws[p][w * 64 + f * 16 + li][g * 8];
#pragma unroll
    for (int i = 0; i < 4; ++i)
#pragma unroll
      for (int jj = 0; jj < 4; ++jj)
        acc[i][jj] = (MODE == 0) ? mfma16(xf[i], wf[jj], acc[i][jj])
                                 : mfma16(wf[i], xf[jj], acc[i][jj]);
    if (kk < 7) {
#pragma unroll
      for (int it = 0; it < 4; ++it)
        *(uint4*)&Ws[p ^ 1][it * 64 + n4][cp << 3] = wr[it];
    }
    __syncthreads();
  }

  if (MODE == 0) {
#pragma unroll
    for (int i = 0; i < 4; ++i)
#pragma unroll
      for (int jj = 0; jj < 4; ++jj)
#pragma unroll
        for (int r = 0; r < 4; ++r) {
          int R = i * 16 + g * 4 + r, C = w * 64 + jj * 16 + li;
          out[(row0 + R) * 256 + C] = f2bf(acc[i][jj][r] + bias[C]);
        }
  } else {
    long b = row0 / Nk, rb = row0 - b * Nk;
#pragma unroll
    for (int i = 0; i < 4; ++i)
#pragma unroll
      for (int jj = 0; jj < 4; ++jj)
#pragma unroll
        for (int r = 0; r < 4; ++r) {
          int e = w * 64 + i * 16 + g * 4 + r, xr = jj * 16 + li;
          out[(b * 256 + e) * (long)Nk + rb + xr] = f2bf(acc[i][jj][r] + bias[e]);
        }
  }
}

// One dispatch per layer: Q-proj + K-proj + V-proj blocks co-resident.
__global__ __launch_bounds__(256, 2) void k_gemm1f(
    const u16* __restrict__ Xq, const u16* __restrict__ Xkv,
    const u16* __restrict__ Wt, const float* __restrict__ beff,
    u16* __restrict__ Qb, u16* __restrict__ Kb, u16* __restrict__ Vt,
    int layer, int Mkv, int Nk) {
  __shared__ __align__(16) u16 Xs[64][264];
  __shared__ __align__(16) u16 Ws[2][256][40];
  int u = blockIdx.x;
  if (u < 256)
    gemm1_body<0>(Xq, Wt + (size_t)layer * 65536, beff + layer * 256, Qb, 0,
                  (long)u * 64, Xs, Ws);
  else if (u < 256 + Mkv)
    gemm1_body<0>(Xkv, Wt + (size_t)(4 + layer) * 65536, beff + (4 + layer) * 256, Kb, 0,
                  (long)(u - 256) * 64, Xs, Ws);
  else
    gemm1_body<1>(Xkv, Wt + (size_t)(8 + layer) * 65536, beff + (8 + layer) * 256, Vt, Nk,
                  (long)(u - 256 - Mkv) * 64, Xs, Ws);
}

// ---------------- flash attention (R3-verified): LDS double-buffer, 1 barrier/iter ------
// Grid 256 x 512thr. Block = 64 q-rows, 8 waves: w -> (qt = w>>1, s = w&1).
// Per 64-k chunk: issue next chunk's global loads to regs (issue-early), compute
// QK (swapped, S[k][q] lane-local) -> exp -> register-shuffle P redistribution ->
// PV, all from XOR-swizzled LDS (conflict-free b128), then ds_write regs, ONE barrier.
__global__ __launch_bounds__(512, 2) void k_attn(
    const u16* __restrict__ Qb, const u16* __restrict__ Kb, const u16* __restrict__ Vt,
    const unsigned* __restrict__ Mb,
    const float* __restrict__ gamma, const float* __restrict__ beta,
    float* xres, u16* xbout,
    const float* __restrict__ future, float* __restrict__ dout, int last, int Nk) {
  __shared__ __align__(16) char RAW[131328];  // 2 x (K 32KB + V 32KB) dbuf; epilogue aliases

  int t = threadIdx.x, lane = t & 63, w = t >> 6;
  int qt = w >> 1, s = w & 1;
  int g = lane >> 4, li = lane & 15;
  int sw = li & 7;

  // XCD-bijective swizzle: XCD x owns batches {2x, 2x+1} -> K/V stays in its L2.
  int n = blockIdx.x;
  int b = ((n & 7) << 1) | ((n >> 3) & 1);
  int q0 = (n >> 4) << 6;

  int W = Nk >> 5, nc = Nk >> 6;

  const u16* Kg = Kb + (long)b * Nk * 256;
  const u16* Vg = Vt + (long)b * 256 * (long)Nk;
  const unsigned* Mg = Mb + ((long)b * 1024 + q0 + qt * 16 + li) * W;
  const u16* Qg = Qb + ((long)b * 1024 + q0 + qt * 16 + li) * 256 + g * 8;

  // Per-thread staging slots (4 K + 4 V), swizzle on the GLOBAL source address:
  // K LDS[row][c] holds global (row, c^(row&7));  V LDS[d][c] holds global (d, c^(d&7)).
  int sA = t, sB = 512 + t, sC = 1024 + t, sD = 1536 + t;
  const u16* KgA = Kg + (long)(sA >> 5) * 256 + (((sA & 31) ^ ((sA >> 5) & 7)) << 3);
  const u16* KgB = Kg + (long)(sB >> 5) * 256 + (((sB & 31) ^ ((sB >> 5) & 7)) << 3);
  const u16* KgC = Kg + (long)(sC >> 5) * 256 + (((sC & 31) ^ ((sC >> 5) & 7)) << 3);
  const u16* KgD = Kg + (long)(sD >> 5) * 256 + (((sD & 31) ^ ((sD >> 5) & 7)) << 3);
  const u16* VgA = Vg + (long)(sA >> 3) * Nk + (((sA & 7) ^ ((sA >> 3) & 7)) << 3);
  const u16* VgB = Vg + (long)(sB >> 3) * Nk + (((sB & 7) ^ ((sB >> 3) & 7)) << 3);
  const u16* VgC = Vg + (long)(sC >> 3) * Nk + (((sC & 7) ^ ((sC >> 3) & 7)) << 3);
  const u16* VgD = Vg + (long)(sD >> 3) * Nk + (((sD & 7) ^ ((sD >> 3) & 7)) << 3);

  // ---- prologue: chunk 0 -> regs, Q frags, chunk 0 -> buf0, barrier ----
  uint4 k0 = *(const uint4*)KgA, k1 = *(const uint4*)KgB;
  uint4 k2 = *(const uint4*)KgC, k3 = *(const uint4*)KgD;
  uint4 v0 = *(const uint4*)VgA, v1 = *(const uint4*)VgB;
  uint4 v2 = *(const uint4*)VgC, v3 = *(const uint4*)VgD;
  bf16x8 qf[8];
#pragma unroll
  for (int kc = 0; kc < 8; ++kc) qf[kc] = *(const bf16x8*)(Qg + kc * 32);
  {
    u16* Kw = (u16*)RAW;
    u16* Vw = Kw + 16384;
    *(uint4*)&Kw[sA * 8] = k0; *(uint4*)&Kw[sB * 8] = k1;
    *(uint4*)&Kw[sC * 8] = k2; *(uint4*)&Kw[sD * 8] = k3;
    *(uint4*)&Vw[sA * 8] = v0; *(uint4*)&Vw[sB * 8] = v1;
    *(uint4*)&Vw[sC * 8] = v2; *(uint4*)&Vw[sD * 8] = v3;
  }
  __syncthreads();

  f32x4 O[16];
#pragma unroll
  for (int dt = 0; dt < 16; ++dt) O[dt] = (f32x4){0.f, 0.f, 0.f, 0.f};
  float lsum = 0.f;

  for (int ci = 0; ci < nc; ++ci) {
    int p = ci & 1;
    // issue next chunk's loads (clamped on last iter; branchless)
    long cb2 = (long)((ci + 1 < nc) ? ci + 1 : nc - 1) << 6;
    k0 = *(const uint4*)(KgA + cb2 * 256); k1 = *(const uint4*)(KgB + cb2 * 256);
    k2 = *(const uint4*)(KgC + cb2 * 256); k3 = *(const uint4*)(KgD + cb2 * 256);
    v0 = *(const uint4*)(VgA + cb2);       v1 = *(const uint4*)(VgB + cb2);
    v2 = *(const uint4*)(VgC + cb2);       v3 = *(const uint4*)(VgD + cb2);
    unsigned mw = Mg[(ci << 1) + s];

    const u16* Kp = (const u16*)(RAW + p * 65536);
    const u16* Vp = Kp + 16384;
    const u16* Kr0 = Kp + (s * 32 + li) * 256;
    const u16* Kr1 = Kr0 + 4096;
    // QK^T swapped: st[t]: k = s*32 + t*16 + g*4 + r (within chunk), q = li
    f32x4 st0 = (f32x4){0.f, 0.f, 0.f, 0.f}, st1 = (f32x4){0.f, 0.f, 0.f, 0.f};
#pragma unroll
    for (int kc = 0; kc < 8; ++kc) {
      int co = ((kc * 4 + g) ^ sw) << 3;
      st0 = mfma16(*(const bf16x8*)&Kr0[co], qf[kc], st0);
      st1 = mfma16(*(const bf16x8*)&Kr1[co], qf[kc], st1);
    }
    float e0[4], e1[4];
#pragma unroll
    for (int r = 0; r < 4; ++r) {
      bool m0 = (mw >> (g * 4 + r)) & 1u;
      bool m1 = (mw >> (16 + g * 4 + r)) & 1u;
      e0[r] = m0 ? 0.f : __expf(st0[r] * 0.0625f);
      e1[r] = m1 ? 0.f : __expf(st1[r] * 0.0625f);
      lsum += e0[r] + e1[r];
    }
    unsigned u00 = (unsigned)f2bf(e0[0]) | ((unsigned)f2bf(e0[1]) << 16);
    unsigned u01 = (unsigned)f2bf(e0[2]) | ((unsigned)f2bf(e0[3]) << 16);
    unsigned u10 = (unsigned)f2bf(e1[0]) | ((unsigned)f2bf(e1[1]) << 16);
    unsigned u11 = (unsigned)f2bf(e1[2]) | ((unsigned)f2bf(e1[3]) << 16);
    int s0l = ((g & 1) << 5) + li;
    unsigned a0 = __shfl(u00, s0l),      a1 = __shfl(u01, s0l);
    unsigned a2 = __shfl(u00, s0l + 16), a3 = __shfl(u01, s0l + 16);
    unsigned c0 = __shfl(u10, s0l),      c1 = __shfl(u11, s0l);
    unsigned c2 = __shfl(u10, s0l + 16), c3 = __shfl(u11, s0l + 16);
    union { unsigned u[4]; bf16x8 v; } pa;
    bool hi = (g >= 2);
    pa.u[0] = hi ? c0 : a0; pa.u[1] = hi ? c1 : a1;
    pa.u[2] = hi ? c2 : a2; pa.u[3] = hi ? c3 : a3;
    // PV: O[q = g*4+r][d = dt*16+li], V^T rows from swizzled LDS
    const u16* Vr = Vp + li * 64 + (((s * 4 + g) ^ sw) << 3);
#pragma unroll
    for (int dt = 0; dt < 16; ++dt) {
      bf16x8 bv = *(const bf16x8*)&Vr[dt * 1024];
      O[dt] = mfma16(pa.v, bv, O[dt]);
    }
    // write-late: next chunk into the other buffer, single barrier
    {
      u16* Kw = (u16*)(RAW + (p ^ 1) * 65536);
      u16* Vw = Kw + 16384;
      *(uint4*)&Kw[sA * 8] = k0; *(uint4*)&Kw[sB * 8] = k1;
      *(uint4*)&Kw[sC * 8] = k2; *(uint4*)&Kw[sD * 8] = k3;
      *(uint4*)&Vw[sA * 8] = v0; *(uint4*)&Vw[sB * 8] = v1;
      *(uint4*)&Vw[sC * 8] = v2; *(uint4*)&Vw[sD * 8] = v3;
    }
    __syncthreads();
  }

  // ---- epilogue: merge s-partials in LDS (aliases staging), LN, +residual ----
  float* Om = (float*)RAW;             // [4][16][260]
  float* Lm = (float*)(RAW + 131072);  // [4][16]
  lsum += __shfl_xor(lsum, 16);
  lsum += __shfl_xor(lsum, 32);        // all lanes: l[q=li] for this s-half
  if (s == 1) {
#pragma unroll
    for (int dt = 0; dt < 16; ++dt)
#pragma unroll
      for (int r = 0; r < 4; ++r)
        Om[(qt * 16 + g * 4 + r) * 260 + dt * 16 + li] = O[dt][r];
    if (g == 0) Lm[qt * 16 + li] = lsum;
  }
  __syncthreads();
  if (s == 0) {
    float rl = 1.f / fmaxf(lsum + Lm[qt * 16 + li], 1e-30f);
    float rq[4];
#pragma unroll
    for (int r = 0; r < 4; ++r) rq[r] = __shfl(rl, g * 4 + r);
    float sm[4] = {0.f, 0.f, 0.f, 0.f}, s2[4] = {0.f, 0.f, 0.f, 0.f};
#pragma unroll
    for (int dt = 0; dt < 16; ++dt)
#pragma unroll
      for (int r = 0; r < 4; ++r) {
        float y = (O[dt][r] + Om[(qt * 16 + g * 4 + r) * 260 + dt * 16 + li]) * rq[r];
        O[dt][r] = y;
        sm[r] += y; s2[r] += y * y;
      }
#pragma unroll
    for (int r = 0; r < 4; ++r) {
      float a = sm[r], c = s2[r];
      a += __shfl_xor(a, 1); a += __shfl_xor(a, 2);
      a += __shfl_xor(a, 4); a += __shfl_xor(a, 8);
      c += __shfl_xor(c, 1); c += __shfl_xor(c, 2);
      c += __shfl_xor(c, 4); c += __shfl_xor(c, 8);
      float m = a * (1.f / 256.f);
      sm[r] = m;
      s2[r] = rsqrtf(c * (1.f / 256.f) - m * m + 1e-5f);
    }
#pragma unroll
    for (int dt = 0; dt < 16; ++dt) {
      int d = dt * 16 + li;
      float gm = gamma[d], bt = beta[d];
#pragma unroll
      for (int r = 0; r < 4; ++r) {
        int q = q0 + qt * 16 + g * 4 + r;
        long idx = ((long)b * 1024 + q) * 256 + d;
        float o = (O[dt][r] - sm[r]) * s2[r] * gm + bt + xres[idx];
        if (last) dout[idx] = o + future[idx];
        else { xres[idx] = o; xbout[idx] = f2bf(o); }
      }
    }
  }
}

// ---------------- host ----------------
extern "C" void kernel_launch(void* const* d_in, const int* in_sizes, int n_in,
                              void* d_out, int out_size, void* d_ws, size_t ws_size,
                              hipStream_t stream) {
  const float* future  = (const float*)d_in[0];
  const float* history = (const float*)d_in[1];
  const float* graph   = (const float*)d_in[2];
  const void*  mask_hf = d_in[3];
  const void*  mask_fg = d_in[4];
  const float* Wq = (const float*)d_in[5];
  const float* bq = (const float*)d_in[6];
  const float* Wk = (const float*)d_in[7];
  const float* bk = (const float*)d_in[8];
  const float* Wv = (const float*)d_in[9];
  const float* bv = (const float*)d_in[10];
  const float* gamma = (const float*)d_in[11];
  const float* beta  = (const float*)d_in[12];
  float* dout = (float*)d_out;

  char* ws = (char*)d_ws;
  size_t off = 0;
  int* flag = (int*)(ws + off); off += 256;
  u16* Wt = (u16*)(ws + off);  off += (size_t)12 * 65536 * 2;
  float* T = (float*)(ws + off); off += (size_t)12 * 65536 * 4;
  float* beff = (float*)(ws + off); off += (size_t)12 * 256 * 4;
  u16* xb = (u16*)(ws + off);  off += (size_t)16384 * 256 * 2;
  float* x = (float*)(ws + off); off += (size_t)16384 * 256 * 4;
  u16* hb = (u16*)(ws + off);  off += (size_t)16384 * 256 * 2;
  u16* gb = (u16*)(ws + off);  off += (size_t)32768 * 256 * 2;
  u16* Qb = (u16*)(ws + off);  off += (size_t)16384 * 256 * 2;
  u16* Kb = (u16*)(ws + off);  off += (size_t)32768 * 256 * 2;
  u16* Vtb = (u16*)(ws + off); off += (size_t)32768 * 256 * 2;
  unsigned* Mbhf = (unsigned*)(ws + off); off += (size_t)16 * 1024 * 1024 / 8;
  unsigned* Mbfg = (unsigned*)(ws + off); off += (size_t)16 * 1024 * 2048 / 8;
  if (ws_size < off) return;

  k_flag<<<1, 64, 0, stream>>>((const unsigned char*)mask_hf, flag);
  k_pack<<<8192, 256, 0, stream>>>(mask_hf, flag, Mbhf);
  k_pack<<<16384, 256, 0, stream>>>(mask_fg, flag, Mbfg);
  k_wc1<<<dim3(256, 12), 256, 0, stream>>>(Wq, Wk, Wv, T);
  k_wc2<<<dim3(16, 12), 256, 0, stream>>>(Wq, Wk, Wv, T, Wt);
  k_bc<<<12, 256, 0, stream>>>(Wq, Wk, Wv, bq, bk, bv, beff);
  k_cvt<<<4096, 256, 0, stream>>>(future, xb, x, 4194304L);
  k_cvt<<<4096, 256, 0, stream>>>(history, hb, nullptr, 4194304L);
  k_cvt<<<8192, 256, 0, stream>>>(graph, gb, nullptr, 8388608L);

  for (int i = 0; i < 4; ++i) {
    const u16* src = (i < 2) ? hb : gb;
    int Mkv = (i < 2) ? 256 : 512;
    int Nk = (i < 2) ? 1024 : 2048;
    const unsigned* mb = (i < 2) ? Mbhf : Mbfg;
    k_gemm1f<<<256 + 2 * Mkv, 256, 0, stream>>>(xb, src, Wt, beff,
                                                Qb, Kb, Vtb, i, Mkv, Nk);
    k_attn<<<256, 512, 0, stream>>>(Qb, Kb, Vtb, mb, gamma + i * 256, beta + i * 256,
                                    x, xb, future, dout, (i == 3) ? 1 : 0, Nk);
  }
}